// Round 1
// 2871.984 us; speedup vs baseline: 1.6246x; 1.6246x over previous
//
#include <hip/hip_runtime.h>

// ---------------- problem constants ----------------
#define NPTS   65536      // 16*4096
#define DIM    1024
#define NCODE  512
#define NLVL   3

// output layout (floats)
#define ZQ_OFF   0
#define LOSS_OFF 67108864
#define IDX_OFF  67108865
#define CB_OFF   67305473

// level-kernel tiling (MFMA version)
#define PB    128         // points per block
#define CBCH  256         // codes per chunk (2 chunks cover 512)
#define KS    64          // K step
#define NTHR2 512

typedef unsigned short u16;
typedef unsigned int   u32;
typedef __attribute__((ext_vector_type(8))) short short8;
typedef __attribute__((ext_vector_type(4))) float f32x4;

// ---------------- helpers ----------------
__device__ inline void merge_top2(float& v1, int& i1, float& v2, int& i2,
                                  float w1, int j1, float w2, int j2) {
    // lexicographic (value, index) min — matches numpy argmin "first min" ties
    bool aFirst = (v1 < w1) || (v1 == w1 && i1 < j1);
    float t1v = aFirst ? v1 : w1; int t1i = aFirst ? i1 : j1;
    float c1v = aFirst ? v2 : w2; int c1i = aFirst ? i2 : j2;
    float c2v = aFirst ? w1 : v1; int c2i = aFirst ? j1 : i1;
    bool cFirst = (c1v < c2v) || (c1v == c2v && c1i < c2i);
    v1 = t1v; i1 = t1i;
    v2 = cFirst ? c1v : c2v;
    i2 = cFirst ? c1i : c2i;
}

__device__ inline u16 bf16_rne(float x) {
    u32 u = __float_as_uint(x);
    u32 r = u + 0x7fffu + ((u >> 16) & 1u);
    return (u16)(r >> 16);
}
__device__ inline float bf16_f(u16 h) { return __uint_as_float(((u32)h) << 16); }

__device__ inline void gload_lds16(const void* g, void* l) {
    __builtin_amdgcn_global_load_lds((const __attribute__((address_space(1))) void*)g,
                                     (__attribute__((address_space(3))) void*)l, 16, 0, 0);
}

// ---------------- codebook row norms (fp32, approx phase only) ----------------
__global__ __launch_bounds__(256) void cnorm_kernel(const float* __restrict__ cb,
                                                    float* __restrict__ cnorm) {
    __shared__ float sd[256];
    const int b = blockIdx.x;          // 0..1535  (l*512+k)
    const int tid = threadIdx.x;
    const float4 v = *(const float4*)&cb[(size_t)b * DIM + tid * 4];
    sd[tid] = v.x*v.x + v.y*v.y + v.z*v.z + v.w*v.w;
    __syncthreads();
    for (int o = 128; o > 0; o >>= 1) { if (tid < o) sd[tid] += sd[tid+o]; __syncthreads(); }
    if (tid == 0) cnorm[b] = sd[0];
}

// ---------------- codebooks -> bf16 hi/lo planes (per level, overlaid on sums ws) ----------------
__global__ __launch_bounds__(256) void cvtcb_kernel(const float* __restrict__ cbs,
                                                    char* __restrict__ planes) {
    const int b = blockIdx.x;          // l*512 + k
    const int tid = threadIdx.x;
    const int l = b >> 9, k = b & 511;
    u16* ph = (u16*)(planes + (size_t)l * 2097152);
    u16* pl = ph + NCODE * DIM;
    const float4 v = *(const float4*)&cbs[(size_t)b * DIM + tid * 4];
    float xs[4] = {v.x, v.y, v.z, v.w};
    u16 hh[4], ll[4];
    #pragma unroll
    for (int e = 0; e < 4; ++e) {
        hh[e] = bf16_rne(xs[e]);
        ll[e] = bf16_rne(xs[e] - bf16_f(hh[e]));
    }
    *(ushort4*)&ph[(size_t)k * DIM + tid * 4] = make_ushort4(hh[0], hh[1], hh[2], hh[3]);
    *(ushort4*)&pl[(size_t)k * DIM + tid * 4] = make_ushort4(ll[0], ll[1], ll[2], ll[3]);
}

// ---------------- per-level MFMA distance + argmin + residual kernel ----------------
// grid = NPTS/PB = 512 blocks, 512 threads (8 waves: 4 code-waves x 2 point-waves).
// Approx distances via bf16 3-pass MFMA (hi*hi + hi*lo + lo*hi); exact decision by
// fp64 top-2 refine (unchanged from the fp32 version).
__global__ __launch_bounds__(512, 2) void level_kernel(
        const float* __restrict__ r_in,      // [NPTS, DIM]
        float* __restrict__ r_out,           // [NPTS, DIM] or null
        const float* __restrict__ cbf,       // [NCODE, DIM] fp32 this level
        const u16* __restrict__ cb_h,        // [NCODE, DIM] bf16 hi plane
        const u16* __restrict__ cb_l,        // [NCODE, DIM] bf16 lo plane
        const float* __restrict__ cnorm_l,   // [NCODE]
        float* __restrict__ out_idx_f,       // [NPTS] float indices
        int*   __restrict__ ws_idx,          // [NPTS] int indices
        float* __restrict__ loss_partial)    // [512] per-block loss partials
{
    // codes tile: [plane][row=code][k], XOR-swizzled 16B slots within 128B rows
    __shared__ u16 sA[2][CBCH][KS];      // 64 KB
    // points tile: [plane][row=point][k], same swizzle
    __shared__ u16 sB[2][PB][KS];        // 32 KB
    __shared__ float s_cn[NCODE];        // 2 KB
    __shared__ float4 s_top[4][PB];      // 8 KB (per code-wave top2 per point)
    __shared__ int s_i1[PB], s_i2[PB], s_w[PB];
    __shared__ double s_ref[PB][2][2];   // 4 KB
    __shared__ float s_red[NTHR2];       // 2 KB

    const int tid  = threadIdx.x;
    const int lane = tid & 63;
    const int wid  = tid >> 6;     // 0..7
    const int wm   = wid >> 1;     // code-wave 0..3 (64 codes each within chunk)
    const int wn   = wid & 1;      // point-wave 0..1 (64 points each)
    const int g    = lane >> 4;    // 0..3
    const int l15  = lane & 15;
    const int pbase = blockIdx.x * PB;

    u16* sAf = &sA[0][0][0];
    u16* sBf = &sB[0][0][0];

    s_cn[tid] = cnorm_l[tid];      // NTHR2 == NCODE == 512

    // per-lane running top-2 per point-slot nf (codes seen by this lane)
    float bv1[4], bv2[4]; int bi1[4], bi2[4];
    #pragma unroll
    for (int i = 0; i < 4; ++i) { bv1[i] = 1e30f; bv2[i] = 1e30f; bi1[i] = 0; bi2[i] = 1; }

    const u16* srcp = (wid < 4) ? cb_h : cb_l;   // waves 0-3 stage hi plane, 4-7 lo plane

    for (int ch = 0; ch < 2; ++ch) {
        const int cbase = ch * CBCH;
        f32x4 acc[4][4] = {};      // [mf][nf], D row=code, col=point

        for (int ks0 = 0; ks0 < DIM; ks0 += KS) {
            __syncthreads();       // prior K-step's ds_reads done before overwrite

            // --- stage A (codes, both planes) via global_load_lds, pre-swizzled source ---
            #pragma unroll
            for (int j = 0; j < 8; ++j) {
                const int cbk = wid * 512 + j * 64;          // wave-uniform chunk base
                const int c   = cbk + lane;                  // 0..4095 (16B chunks)
                const int cc  = c & 2047;                    // within plane
                const int row = cc >> 3, slot = cc & 7;
                const u16* gp = srcp + (size_t)(cbase + row) * DIM + ks0
                                + ((slot ^ (row & 7)) << 3); // inverse-swizzled source
                gload_lds16(gp, sAf + (size_t)cbk * 8);      // linear LDS dest
            }

            // --- stage B (points) reg-staged fp32 -> bf16 hi/lo, swizzled ds_write ---
            #pragma unroll
            for (int j = 0; j < 2; ++j) {
                const int s = tid + j * 512;                 // 0..1023 (row,slot)
                const int row = s >> 3, slot = s & 7;
                const float* gp = r_in + (size_t)(pbase + row) * DIM + ks0 + slot * 8;
                const float4 a0 = *(const float4*)gp;
                const float4 a1 = *(const float4*)(gp + 4);
                float xs[8] = {a0.x, a0.y, a0.z, a0.w, a1.x, a1.y, a1.z, a1.w};
                short8 h8, l8;
                #pragma unroll
                for (int e = 0; e < 8; ++e) {
                    const u16 hb = bf16_rne(xs[e]);
                    const u16 lb = bf16_rne(xs[e] - bf16_f(hb));
                    h8[e] = (short)hb; l8[e] = (short)lb;
                }
                const int woff = row * KS + ((slot ^ (row & 7)) << 3);
                *(short8*)(sBf + woff) = h8;
                *(short8*)(sBf + 8192 + woff) = l8;
            }
            asm volatile("s_waitcnt vmcnt(0)" ::: "memory"); // drain global_load_lds
            __syncthreads();

            // --- MFMA: acc += Ahi*Bhi + Ahi*Blo + Alo*Bhi ---
            #pragma unroll
            for (int ksub = 0; ksub < 2; ++ksub) {
                const int rsw = (((ksub << 2) + g) ^ (lane & 7)) << 3;  // swizzled k-slot (row&7==lane&7)
                short8 bh[4], bl[4];
                #pragma unroll
                for (int nf = 0; nf < 4; ++nf) {
                    const int row = wn * 64 + nf * 16 + l15;
                    bh[nf] = *(const short8*)(sBf + row * KS + rsw);
                    bl[nf] = *(const short8*)(sBf + 8192 + row * KS + rsw);
                }
                #pragma unroll
                for (int mf = 0; mf < 4; ++mf) {
                    const int row = wm * 64 + mf * 16 + l15;
                    const short8 ah = *(const short8*)(sAf + row * KS + rsw);
                    const short8 al = *(const short8*)(sAf + 16384 + row * KS + rsw);
                    #pragma unroll
                    for (int nf = 0; nf < 4; ++nf) {
                        acc[mf][nf] = __builtin_amdgcn_mfma_f32_16x16x32_bf16(ah, bh[nf], acc[mf][nf], 0, 0, 0);
                        acc[mf][nf] = __builtin_amdgcn_mfma_f32_16x16x32_bf16(ah, bl[nf], acc[mf][nf], 0, 0, 0);
                        acc[mf][nf] = __builtin_amdgcn_mfma_f32_16x16x32_bf16(al, bh[nf], acc[mf][nf], 0, 0, 0);
                    }
                }
            }
        }

        // --- fold chunk into per-lane running top-2 (codes ascending per lane) ---
        #pragma unroll
        for (int nf = 0; nf < 4; ++nf)
            #pragma unroll
            for (int mf = 0; mf < 4; ++mf)
                #pragma unroll
                for (int r = 0; r < 4; ++r) {
                    const int code = cbase + wm * 64 + mf * 16 + g * 4 + r;
                    const float sv = s_cn[code] - 2.0f * acc[mf][nf][r];
                    if (sv < bv1[nf])      { bv2[nf] = bv1[nf]; bi2[nf] = bi1[nf]; bv1[nf] = sv; bi1[nf] = code; }
                    else if (sv < bv2[nf]) { bv2[nf] = sv; bi2[nf] = code; }
                }
    }

    // --- cross-lane (g groups) reduce, publish per code-wave top-2 ---
    #pragma unroll
    for (int nf = 0; nf < 4; ++nf) {
        float v1 = bv1[nf], v2 = bv2[nf]; int i1 = bi1[nf], i2 = bi2[nf];
        #pragma unroll
        for (int m = 16; m < 64; m <<= 1) {
            const float w1 = __shfl_xor(v1, m); const int j1 = __shfl_xor(i1, m);
            const float w2 = __shfl_xor(v2, m); const int j2 = __shfl_xor(i2, m);
            merge_top2(v1, i1, v2, i2, w1, j1, w2, j2);
        }
        if (g == 0)
            s_top[wm][wn * 64 + nf * 16 + l15] =
                make_float4(v1, __int_as_float(i1), v2, __int_as_float(i2));
    }
    __syncthreads();

    // --- cross-wave (wm) final top-2 merge ---
    if (tid < PB) {
        float4 t = s_top[0][tid];
        float v1 = t.x; int i1 = __float_as_int(t.y);
        float v2 = t.z; int i2 = __float_as_int(t.w);
        #pragma unroll
        for (int wmm = 1; wmm < 4; ++wmm) {
            const float4 u = s_top[wmm][tid];
            merge_top2(v1, i1, v2, i2, u.x, __float_as_int(u.y), u.z, __float_as_int(u.w));
        }
        s_i1[tid] = i1; s_i2[tid] = i2;
    }
    __syncthreads();

    // --- fp64 refine: 512 tasks = 128 points x 2 candidates x 2 halves ---
    {
        const int p = tid >> 2, cand = (tid >> 1) & 1, half = tid & 1;
        const int k = cand ? s_i2[p] : s_i1[p];
        const float* rr = r_in + (size_t)(pbase + p) * DIM + half * 512;
        const float* cr = cbf + (size_t)k * DIM + half * 512;
        double s = 0.0;
        for (int d = 0; d < 512; ++d) {
            const double c = (double)cr[d];
            const double r = (double)rr[d];
            s += c * (c - 2.0 * r);
        }
        s_ref[p][cand][half] = s;
    }
    __syncthreads();
    if (tid < PB) {
        const double sA_ = s_ref[tid][0][0] + s_ref[tid][0][1];
        const double sB_ = s_ref[tid][1][0] + s_ref[tid][1][1];
        const int iA = s_i1[tid], iB = s_i2[tid];
        const int w = (sB_ < sA_ || (sB_ == sA_ && iB < iA)) ? iB : iA;
        s_w[tid] = w;
        out_idx_f[pbase + tid] = (float)w;
        ws_idx[pbase + tid] = w;
    }
    __syncthreads();

    // --- residual update + commitment-loss partial ---
    float lsum = 0.f;
    const int colb = (tid & 255) * 4;
    const int phh  = tid >> 8;           // 0 or 1
    for (int pp = 0; pp < PB; pp += 2) {
        const int p = pp + phh;
        const int w = s_w[p];
        const size_t off = (size_t)(pbase + p) * DIM + colb;
        const float4 rv = *(const float4*)&r_in[off];
        const float4 cv = *(const float4*)&cbf[(size_t)w * DIM + colb];
        float4 rn;
        rn.x = rv.x - cv.x; rn.y = rv.y - cv.y; rn.z = rv.z - cv.z; rn.w = rv.w - cv.w;
        if (r_out) *(float4*)&r_out[off] = rn;
        lsum += rn.x*rn.x + rn.y*rn.y + rn.z*rn.z + rn.w*rn.w;
    }
    s_red[tid] = lsum;
    __syncthreads();
    for (int o = 256; o > 0; o >>= 1) { if (tid < o) s_red[tid] += s_red[tid + o]; __syncthreads(); }
    if (tid == 0) loss_partial[blockIdx.x] = s_red[0];
}

// ---------------- deterministic bucket sums (no atomics) ----------------
#define SCHUNK 4096
__global__ __launch_bounds__(256) void sums_kernel(
        const int* __restrict__ idx, const float* __restrict__ src,
        const float* __restrict__ cb, int addC,
        float* __restrict__ sums_out, int* __restrict__ counts_out)
{
    __shared__ int s_idx[SCHUNK];
    __shared__ int s_list[SCHUNK];
    __shared__ int s_scan[256];
    const int k = blockIdx.x, tid = threadIdx.x;
    float4 acc = make_float4(0.f, 0.f, 0.f, 0.f);
    int nk = 0;
    for (int base = 0; base < NPTS; base += SCHUNK) {
        __syncthreads();
        for (int j = tid; j < SCHUNK; j += 256) s_idx[j] = idx[base + j];
        __syncthreads();
        int cnt = 0;
        const int S = SCHUNK / 256;   // 16
        #pragma unroll
        for (int j = 0; j < S; ++j) cnt += (s_idx[tid * S + j] == k);
        s_scan[tid] = cnt;
        __syncthreads();
        for (int off = 1; off < 256; off <<= 1) {
            int v = (tid >= off) ? s_scan[tid - off] : 0;
            __syncthreads();
            s_scan[tid] += v;
            __syncthreads();
        }
        const int total = s_scan[255];
        int pos = s_scan[tid] - cnt;
        for (int j = 0; j < S; ++j)
            if (s_idx[tid * S + j] == k) s_list[pos++] = base + tid * S + j;
        __syncthreads();
        for (int j = 0; j < total; ++j) {
            const int pid = s_list[j];
            float4 v = *(const float4*)&src[(size_t)pid * DIM + tid * 4];
            acc.x += v.x; acc.y += v.y; acc.z += v.z; acc.w += v.w;
        }
        nk += total;
    }
    if (addC) {   // src was post-update residual: add back nk * C[k]
        float4 c = *(const float4*)&cb[(size_t)k * DIM + tid * 4];
        float fn = (float)nk;
        acc.x += fn * c.x; acc.y += fn * c.y; acc.z += fn * c.z; acc.w += fn * c.w;
    }
    *(float4*)&sums_out[(size_t)k * DIM + tid * 4] = acc;
    if (tid == 0) counts_out[k] = nk;
}

// ---------------- z_q_st = z_e - r2 + C2[idx2] (in-place on zq/r2 buffer) ----------------
__global__ __launch_bounds__(256) void zq_kernel(const float* __restrict__ z_e,
                                                 const float* __restrict__ cb2,
                                                 const int* __restrict__ idx2,
                                                 float* __restrict__ zq) {
    const int total = NPTS * (DIM / 4);   // float4 count = 16777216
    for (int i = blockIdx.x * 256 + threadIdx.x; i < total; i += gridDim.x * 256) {
        const size_t e = (size_t)i * 4;
        const int p = (int)(e >> 10);
        const int d = (int)(e & 1023);
        const int w = idx2[p];
        float4 z = *(const float4*)&z_e[e];
        float4 r = *(const float4*)&zq[e];
        float4 c = *(const float4*)&cb2[(size_t)w * DIM + d];
        float4 o;
        o.x = z.x - r.x + c.x; o.y = z.y - r.y + c.y;
        o.z = z.z - r.z + c.z; o.w = z.w - r.w + c.w;
        *(float4*)&zq[e] = o;
    }
}

// ---------------- n[l] = sum_k (0.99*ema_cluster + 0.01*counts) ----------------
__global__ __launch_bounds__(512) void nsum_kernel(const float* __restrict__ ec,
                                                   const int* __restrict__ counts,
                                                   float* __restrict__ n_ws) {
    __shared__ float sd[512];
    const int l = blockIdx.x, tid = threadIdx.x;
    sd[tid] = 0.99f * ec[l * NCODE + tid] + 0.01f * (float)counts[l * NCODE + tid];
    __syncthreads();
    for (int o = 256; o > 0; o >>= 1) { if (tid < o) sd[tid] += sd[tid+o]; __syncthreads(); }
    if (tid == 0) n_ws[l] = sd[0];
}

// ---------------- new_codebooks = (0.99*ema_w + 0.01*sums) / cs_norm ----------------
__global__ __launch_bounds__(256) void newcb_kernel(const float* __restrict__ ema_w,
                                                    const float* __restrict__ sums,
                                                    const float* __restrict__ ec,
                                                    const int* __restrict__ counts,
                                                    const float* __restrict__ n_ws,
                                                    float* __restrict__ out_cb) {
    const int b = blockIdx.x;          // l*512 + k
    const int tid = threadIdx.x;
    const int l = b >> 9;
    const float cs = 0.99f * ec[b] + 0.01f * (float)counts[b];
    const float n = n_ws[l];
    const float csn = (cs + 1e-5f) / (n + 512.0f * 1e-5f) * n;
    const size_t off = (size_t)b * DIM + tid * 4;
    float4 w = *(const float4*)&ema_w[off];
    float4 s4 = *(const float4*)&sums[off];
    float4 o;
    o.x = (0.99f * w.x + 0.01f * s4.x) / csn;
    o.y = (0.99f * w.y + 0.01f * s4.y) / csn;
    o.z = (0.99f * w.z + 0.01f * s4.z) / csn;
    o.w = (0.99f * w.w + 0.01f * s4.w) / csn;
    *(float4*)&out_cb[off] = o;
}

// ---------------- loss scalar ----------------
__global__ __launch_bounds__(256) void loss_kernel(const float* __restrict__ lp,
                                                   float* __restrict__ out_loss) {
    __shared__ double sd[256];
    const int tid = threadIdx.x;
    const double commit[3] = {0.25, 0.5, 1.0};
    double acc = 0.0;
    for (int l = 0; l < NLVL; ++l) {
        double s = 0.0;
        for (int j = tid; j < 512; j += 256) s += (double)lp[l * 512 + j];
        sd[tid] = s;
        __syncthreads();
        for (int o = 128; o > 0; o >>= 1) { if (tid < o) sd[tid] += sd[tid+o]; __syncthreads(); }
        if (tid == 0) acc += commit[l] * sd[0] / 67108864.0;
        __syncthreads();
    }
    if (tid == 0) *out_loss = (float)acc;
}

// ---------------- launcher ----------------
extern "C" void kernel_launch(void* const* d_in, const int* in_sizes, int n_in,
                              void* d_out, int out_size, void* d_ws, size_t ws_size,
                              hipStream_t stream) {
    const float* z_e   = (const float*)d_in[0];   // [16,4096,1024]
    const float* cbs   = (const float*)d_in[1];   // [3,512,1024]
    const float* ema_c = (const float*)d_in[2];   // [3,512]
    const float* ema_w = (const float*)d_in[3];   // [3,512,1024]
    float* out = (float*)d_out;

    char* ws = (char*)d_ws;
    int*   ws_idx = (int*)ws;                      // 3*65536 ints      (786432 B)
    float* cnorm  = (float*)(ws + 786432);         // 1536 floats
    int*   counts = (int*)(ws + 792576);           // 1536 ints
    float* lossp  = (float*)(ws + 798720);         // 3*512 floats used (3*1024 reserved)
    float* n_ws   = (float*)(ws + 811008);         // 3 floats (pad to 16)
    float* sums   = (float*)(ws + 811024);         // 3*512*1024 floats (~6 MB)
    char*  planes = (char*)(ws + 811024);          // bf16 hi/lo planes OVERLAY sums:
                                                   // plane[l] (2 MB) dead before sums[l] written

    float* zq       = out + ZQ_OFF;     // doubles as residual buffer
    float* out_loss = out + LOSS_OFF;
    float* out_idx  = out + IDX_OFF;
    float* out_cb   = out + CB_OFF;

    const float* cb0 = cbs;
    const float* cb1 = cbs + (size_t)1 * NCODE * DIM;
    const float* cb2 = cbs + (size_t)2 * NCODE * DIM;

    u16* ph0 = (u16*)(planes);                     u16* pl0 = ph0 + NCODE * DIM;
    u16* ph1 = (u16*)(planes + 2097152);           u16* pl1 = ph1 + NCODE * DIM;
    u16* ph2 = (u16*)(planes + 2 * 2097152);       u16* pl2 = ph2 + NCODE * DIM;

    cvtcb_kernel<<<NLVL * NCODE, 256, 0, stream>>>(cbs, planes);
    cnorm_kernel<<<NLVL * NCODE, 256, 0, stream>>>(cbs, cnorm);

    // level 0: r_in = z_e, r1 -> zq buffer
    level_kernel<<<NPTS / PB, NTHR2, 0, stream>>>(z_e, zq, cb0, ph0, pl0, cnorm,
                                                  out_idx, ws_idx, lossp);
    // sums_0 over pre-residual = z_e (overwrites plane 0 region — plane 0 dead)
    sums_kernel<<<NCODE, 256, 0, stream>>>(ws_idx, z_e, nullptr, 0,
                                           sums, counts);
    // level 1: in-place r1 -> r2 in zq buffer
    level_kernel<<<NPTS / PB, NTHR2, 0, stream>>>(zq, zq, cb1, ph1, pl1, cnorm + NCODE,
                                                  out_idx + NPTS, ws_idx + NPTS, lossp + 512);
    // sums_1 via post-residual trick: sum(r2 in bucket) + nk*C1[k]
    sums_kernel<<<NCODE, 256, 0, stream>>>(ws_idx + NPTS, zq, cb1, 1,
                                           sums + (size_t)NCODE * DIM, counts + NCODE);
    // level 2: r_in = r2 (kept intact), residual only in registers
    level_kernel<<<NPTS / PB, NTHR2, 0, stream>>>(zq, nullptr, cb2, ph2, pl2, cnorm + 2 * NCODE,
                                                  out_idx + 2 * NPTS, ws_idx + 2 * NPTS, lossp + 1024);
    // sums_2 over pre-residual = r2 (still intact in zq buffer)
    sums_kernel<<<NCODE, 256, 0, stream>>>(ws_idx + 2 * NPTS, zq, nullptr, 0,
                                           sums + (size_t)2 * NCODE * DIM, counts + 2 * NCODE);
    // z_q_st = z_e - r2 + C2[idx2], in-place overwrite of zq buffer
    zq_kernel<<<4096, 256, 0, stream>>>(z_e, cb2, ws_idx + 2 * NPTS, zq);

    nsum_kernel<<<NLVL, 512, 0, stream>>>(ema_c, counts, n_ws);
    newcb_kernel<<<NLVL * NCODE, 256, 0, stream>>>(ema_w, sums, ema_c, counts, n_ws, out_cb);
    loss_kernel<<<1, 256, 0, stream>>>(lossp, out_loss);
}

// Round 2
// 2648.414 us; speedup vs baseline: 1.7617x; 1.0844x over previous
//
#include <hip/hip_runtime.h>

// ---------------- problem constants ----------------
#define NPTS   65536      // 16*4096
#define DIM    1024
#define NCODE  512
#define NLVL   3

// output layout (floats)
#define ZQ_OFF   0
#define LOSS_OFF 67108864
#define IDX_OFF  67108865
#define CB_OFF   67305473

// level-kernel tiling (MFMA version)
#define PB    128         // points per block
#define CBCH  256         // codes per chunk (2 chunks cover 512)
#define KS    32          // K step (32 -> 48 KB staging, 2 blocks/CU)
#define NTHR2 512

typedef unsigned short u16;
typedef unsigned int   u32;
typedef __attribute__((ext_vector_type(8))) short short8;
typedef __attribute__((ext_vector_type(4))) float f32x4;

// ---------------- helpers ----------------
__device__ inline void merge_top2(float& v1, int& i1, float& v2, int& i2,
                                  float w1, int j1, float w2, int j2) {
    // lexicographic (value, index) min — matches numpy argmin "first min" ties
    bool aFirst = (v1 < w1) || (v1 == w1 && i1 < j1);
    float t1v = aFirst ? v1 : w1; int t1i = aFirst ? i1 : j1;
    float c1v = aFirst ? v2 : w2; int c1i = aFirst ? i2 : j2;
    float c2v = aFirst ? w1 : v1; int c2i = aFirst ? j1 : i1;
    bool cFirst = (c1v < c2v) || (c1v == c2v && c1i < c2i);
    v1 = t1v; i1 = t1i;
    v2 = cFirst ? c1v : c2v;
    i2 = cFirst ? c1i : c2i;
}

__device__ inline u16 bf16_rne(float x) {
    u32 u = __float_as_uint(x);
    u32 r = u + 0x7fffu + ((u >> 16) & 1u);
    return (u16)(r >> 16);
}
__device__ inline float bf16_f(u16 h) { return __uint_as_float(((u32)h) << 16); }

__device__ inline void gload_lds16(const void* g, void* l) {
    __builtin_amdgcn_global_load_lds((const __attribute__((address_space(1))) void*)g,
                                     (__attribute__((address_space(3))) void*)l, 16, 0, 0);
}

// ---------------- codebook row norms (fp32, approx phase only) ----------------
__global__ __launch_bounds__(256) void cnorm_kernel(const float* __restrict__ cb,
                                                    float* __restrict__ cnorm) {
    __shared__ float sd[256];
    const int b = blockIdx.x;          // 0..1535  (l*512+k)
    const int tid = threadIdx.x;
    const float4 v = *(const float4*)&cb[(size_t)b * DIM + tid * 4];
    sd[tid] = v.x*v.x + v.y*v.y + v.z*v.z + v.w*v.w;
    __syncthreads();
    for (int o = 128; o > 0; o >>= 1) { if (tid < o) sd[tid] += sd[tid+o]; __syncthreads(); }
    if (tid == 0) cnorm[b] = sd[0];
}

// ---------------- codebooks -> bf16 hi/lo planes (per level, overlaid on sums ws) ----------------
__global__ __launch_bounds__(256) void cvtcb_kernel(const float* __restrict__ cbs,
                                                    char* __restrict__ planes) {
    const int b = blockIdx.x;          // l*512 + k
    const int tid = threadIdx.x;
    const int l = b >> 9, k = b & 511;
    u16* ph = (u16*)(planes + (size_t)l * 2097152);
    u16* pl = ph + NCODE * DIM;
    const float4 v = *(const float4*)&cbs[(size_t)b * DIM + tid * 4];
    float xs[4] = {v.x, v.y, v.z, v.w};
    u16 hh[4], ll[4];
    #pragma unroll
    for (int e = 0; e < 4; ++e) {
        hh[e] = bf16_rne(xs[e]);
        ll[e] = bf16_rne(xs[e] - bf16_f(hh[e]));
    }
    *(ushort4*)&ph[(size_t)k * DIM + tid * 4] = make_ushort4(hh[0], hh[1], hh[2], hh[3]);
    *(ushort4*)&pl[(size_t)k * DIM + tid * 4] = make_ushort4(ll[0], ll[1], ll[2], ll[3]);
}

// ---------------- per-level MFMA distance + argmin + residual kernel ----------------
// grid = NPTS/PB = 512 blocks, 512 threads (8 waves: 4 code-waves x 2 point-waves).
// KS=32 + tail-overlay union keeps LDS at 50 KB -> 2 blocks/CU (VGPR-capped), so
// block tails (fp64 refine / residual) overlap neighbor blocks' MFMA phase.
__global__ __launch_bounds__(512, 4) void level_kernel(
        const float* __restrict__ r_in,      // [NPTS, DIM]
        float* __restrict__ r_out,           // [NPTS, DIM] or null
        const float* __restrict__ cbf,       // [NCODE, DIM] fp32 this level
        const u16* __restrict__ cb_h,        // [NCODE, DIM] bf16 hi plane
        const u16* __restrict__ cb_l,        // [NCODE, DIM] bf16 lo plane
        const float* __restrict__ cnorm_l,   // [NCODE]
        float* __restrict__ out_idx_f,       // [NPTS] float indices
        int*   __restrict__ ws_idx,          // [NPTS] int indices
        float* __restrict__ loss_partial)    // [512] per-block loss partials
{
    // staging (distance phase) and tail arrays have disjoint lifetimes -> union
    __shared__ union {
        struct {
            u16 A[2][CBCH][KS];   // 32 KB codes tile, [plane][row][k], swizzled 16B slots
            u16 B[2][PB][KS];     // 16 KB points tile, same swizzle
        } st;
        struct {
            float4 top[4][PB];    // 8 KB per-code-wave top2 per point
            double ref[PB][2][2]; // 4 KB
            int    i1[PB], i2[PB], w[PB];
            float  red[NTHR2];
        } tl;
    } sm;
    __shared__ float s_cn[NCODE];    // persists across chunks -> not overlaid

    const int tid  = threadIdx.x;
    const int lane = tid & 63;
    const int wid  = tid >> 6;     // 0..7
    const int wm   = wid >> 1;     // code-wave 0..3 (64 codes each within chunk)
    const int wn   = wid & 1;      // point-wave 0..1 (64 points each)
    const int g    = lane >> 4;    // 0..3
    const int l15  = lane & 15;
    const int fr   = (l15 >> 1) & 3;  // swizzle term: (row>>1)&3 with row = 16*X + l15
    const int pbase = blockIdx.x * PB;

    u16* sAf = &sm.st.A[0][0][0];
    u16* sBf = &sm.st.B[0][0][0];

    s_cn[tid] = cnorm_l[tid];      // NTHR2 == NCODE == 512

    // per-lane running top-2 per point-slot nf (codes seen by this lane)
    float bv1[4], bv2[4]; int bi1[4], bi2[4];
    #pragma unroll
    for (int i = 0; i < 4; ++i) { bv1[i] = 1e30f; bv2[i] = 1e30f; bi1[i] = 0; bi2[i] = 1; }

    const u16* srcp = (wid < 4) ? cb_h : cb_l;   // waves 0-3 stage hi plane, 4-7 lo plane

    for (int ch = 0; ch < 2; ++ch) {
        const int cbase = ch * CBCH;
        f32x4 acc[4][4] = {};      // [mf][nf], D row=code, col=point

        for (int ks0 = 0; ks0 < DIM; ks0 += KS) {
            __syncthreads();       // prior K-step's ds_reads done before overwrite

            // --- stage A (codes, both planes) via global_load_lds, pre-swizzled source ---
            // 2048 16B-chunks: chunk = plane*1024 + row*4 + slot
            #pragma unroll
            for (int j = 0; j < 4; ++j) {
                const int c   = wid * 256 + j * 64 + lane;   // wave-uniform base + lane
                const int cc  = c & 1023;                    // within plane
                const int row = cc >> 2, slot = cc & 3;
                const u16* gp = srcp + (size_t)(cbase + row) * DIM + ks0
                                + ((slot ^ ((row >> 1) & 3)) << 3); // inverse-swizzled source
                gload_lds16(gp, sAf + (size_t)c * 8);        // linear LDS dest
            }

            // --- stage B (points) reg-staged fp32 -> bf16 hi/lo, swizzled ds_write ---
            {
                const int row = tid >> 2, slot = tid & 3;    // 128 rows x 4 slots
                const float* gp = r_in + (size_t)(pbase + row) * DIM + ks0 + slot * 8;
                const float4 a0 = *(const float4*)gp;
                const float4 a1 = *(const float4*)(gp + 4);
                float xs[8] = {a0.x, a0.y, a0.z, a0.w, a1.x, a1.y, a1.z, a1.w};
                short8 h8, l8;
                #pragma unroll
                for (int e = 0; e < 8; ++e) {
                    const u16 hb = bf16_rne(xs[e]);
                    const u16 lb = bf16_rne(xs[e] - bf16_f(hb));
                    h8[e] = (short)hb; l8[e] = (short)lb;
                }
                const int woff = row * KS + ((slot ^ ((row >> 1) & 3)) << 3);
                *(short8*)(sBf + woff) = h8;
                *(short8*)(sBf + 4096 + woff) = l8;
            }
            asm volatile("s_waitcnt vmcnt(0)" ::: "memory"); // drain global_load_lds
            __syncthreads();

            // --- MFMA: acc += Ahi*Bhi + Ahi*Blo + Alo*Bhi ---
            {
                const int ksl = (g ^ fr) << 3;               // swizzled k-slot for this lane
                short8 bh[4], bl[4];
                #pragma unroll
                for (int nf = 0; nf < 4; ++nf) {
                    const int row = wn * 64 + nf * 16 + l15;
                    bh[nf] = *(const short8*)(sBf + row * KS + ksl);
                    bl[nf] = *(const short8*)(sBf + 4096 + row * KS + ksl);
                }
                #pragma unroll
                for (int mf = 0; mf < 4; ++mf) {
                    const int row = wm * 64 + mf * 16 + l15;
                    const short8 ah = *(const short8*)(sAf + row * KS + ksl);
                    const short8 al = *(const short8*)(sAf + 8192 + row * KS + ksl);
                    #pragma unroll
                    for (int nf = 0; nf < 4; ++nf) {
                        acc[mf][nf] = __builtin_amdgcn_mfma_f32_16x16x32_bf16(ah, bh[nf], acc[mf][nf], 0, 0, 0);
                        acc[mf][nf] = __builtin_amdgcn_mfma_f32_16x16x32_bf16(ah, bl[nf], acc[mf][nf], 0, 0, 0);
                        acc[mf][nf] = __builtin_amdgcn_mfma_f32_16x16x32_bf16(al, bh[nf], acc[mf][nf], 0, 0, 0);
                    }
                }
            }
        }

        // --- fold chunk into per-lane running top-2 (registers + s_cn only) ---
        #pragma unroll
        for (int nf = 0; nf < 4; ++nf)
            #pragma unroll
            for (int mf = 0; mf < 4; ++mf)
                #pragma unroll
                for (int r = 0; r < 4; ++r) {
                    const int code = cbase + wm * 64 + mf * 16 + g * 4 + r;
                    const float sv = s_cn[code] - 2.0f * acc[mf][nf][r];
                    if (sv < bv1[nf])      { bv2[nf] = bv1[nf]; bi2[nf] = bi1[nf]; bv1[nf] = sv; bi1[nf] = code; }
                    else if (sv < bv2[nf]) { bv2[nf] = sv; bi2[nf] = code; }
                }
    }

    __syncthreads();   // staging lifetime ends; tail overlay begins

    // --- cross-lane (g groups) reduce, publish per code-wave top-2 ---
    #pragma unroll
    for (int nf = 0; nf < 4; ++nf) {
        float v1 = bv1[nf], v2 = bv2[nf]; int i1 = bi1[nf], i2 = bi2[nf];
        #pragma unroll
        for (int m = 16; m < 64; m <<= 1) {
            const float w1 = __shfl_xor(v1, m); const int j1 = __shfl_xor(i1, m);
            const float w2 = __shfl_xor(v2, m); const int j2 = __shfl_xor(i2, m);
            merge_top2(v1, i1, v2, i2, w1, j1, w2, j2);
        }
        if (g == 0)
            sm.tl.top[wm][wn * 64 + nf * 16 + l15] =
                make_float4(v1, __int_as_float(i1), v2, __int_as_float(i2));
    }
    __syncthreads();

    // --- cross-wave (wm) final top-2 merge ---
    if (tid < PB) {
        float4 t = sm.tl.top[0][tid];
        float v1 = t.x; int i1 = __float_as_int(t.y);
        float v2 = t.z; int i2 = __float_as_int(t.w);
        #pragma unroll
        for (int wmm = 1; wmm < 4; ++wmm) {
            const float4 u = sm.tl.top[wmm][tid];
            merge_top2(v1, i1, v2, i2, u.x, __float_as_int(u.y), u.z, __float_as_int(u.w));
        }
        sm.tl.i1[tid] = i1; sm.tl.i2[tid] = i2;
    }
    __syncthreads();

    // --- fp64 refine: 512 tasks = 128 points x 2 candidates x 2 halves ---
    // float4 loads + 4 independent accumulators (breaks the dependent f64 chain)
    {
        const int p = tid >> 2, cand = (tid >> 1) & 1, half = tid & 1;
        const int k = cand ? sm.tl.i2[p] : sm.tl.i1[p];
        const float4* rr = (const float4*)(r_in + (size_t)(pbase + p) * DIM + half * 512);
        const float4* cr = (const float4*)(cbf + (size_t)k * DIM + half * 512);
        double s0 = 0.0, s1 = 0.0, s2 = 0.0, s3 = 0.0;
        for (int d = 0; d < 128; ++d) {
            const float4 c4 = cr[d];
            const float4 r4 = rr[d];
            s0 += (double)c4.x * ((double)c4.x - 2.0 * (double)r4.x);
            s1 += (double)c4.y * ((double)c4.y - 2.0 * (double)r4.y);
            s2 += (double)c4.z * ((double)c4.z - 2.0 * (double)r4.z);
            s3 += (double)c4.w * ((double)c4.w - 2.0 * (double)r4.w);
        }
        sm.tl.ref[p][cand][half] = (s0 + s1) + (s2 + s3);
    }
    __syncthreads();
    if (tid < PB) {
        const double sA_ = sm.tl.ref[tid][0][0] + sm.tl.ref[tid][0][1];
        const double sB_ = sm.tl.ref[tid][1][0] + sm.tl.ref[tid][1][1];
        const int iA = sm.tl.i1[tid], iB = sm.tl.i2[tid];
        const int w = (sB_ < sA_ || (sB_ == sA_ && iB < iA)) ? iB : iA;
        sm.tl.w[tid] = w;
        out_idx_f[pbase + tid] = (float)w;
        ws_idx[pbase + tid] = w;
    }
    __syncthreads();

    // --- residual update + commitment-loss partial ---
    float lsum = 0.f;
    const int colb = (tid & 255) * 4;
    const int phh  = tid >> 8;           // 0 or 1
    for (int pp = 0; pp < PB; pp += 2) {
        const int p = pp + phh;
        const int w = sm.tl.w[p];
        const size_t off = (size_t)(pbase + p) * DIM + colb;
        const float4 rv = *(const float4*)&r_in[off];
        const float4 cv = *(const float4*)&cbf[(size_t)w * DIM + colb];
        float4 rn;
        rn.x = rv.x - cv.x; rn.y = rv.y - cv.y; rn.z = rv.z - cv.z; rn.w = rv.w - cv.w;
        if (r_out) *(float4*)&r_out[off] = rn;
        lsum += rn.x*rn.x + rn.y*rn.y + rn.z*rn.z + rn.w*rn.w;
    }
    sm.tl.red[tid] = lsum;
    __syncthreads();
    for (int o = 256; o > 0; o >>= 1) { if (tid < o) sm.tl.red[tid] += sm.tl.red[tid + o]; __syncthreads(); }
    if (tid == 0) loss_partial[blockIdx.x] = sm.tl.red[0];
}

// ---------------- deterministic bucket sums (no atomics) ----------------
#define SCHUNK 4096
__global__ __launch_bounds__(256) void sums_kernel(
        const int* __restrict__ idx, const float* __restrict__ src,
        const float* __restrict__ cb, int addC,
        float* __restrict__ sums_out, int* __restrict__ counts_out)
{
    __shared__ int s_idx[SCHUNK];
    __shared__ int s_list[SCHUNK];
    __shared__ int s_scan[256];
    const int k = blockIdx.x, tid = threadIdx.x;
    float4 acc = make_float4(0.f, 0.f, 0.f, 0.f);
    int nk = 0;
    for (int base = 0; base < NPTS; base += SCHUNK) {
        __syncthreads();
        for (int j = tid; j < SCHUNK; j += 256) s_idx[j] = idx[base + j];
        __syncthreads();
        int cnt = 0;
        const int S = SCHUNK / 256;   // 16
        #pragma unroll
        for (int j = 0; j < S; ++j) cnt += (s_idx[tid * S + j] == k);
        s_scan[tid] = cnt;
        __syncthreads();
        for (int off = 1; off < 256; off <<= 1) {
            int v = (tid >= off) ? s_scan[tid - off] : 0;
            __syncthreads();
            s_scan[tid] += v;
            __syncthreads();
        }
        const int total = s_scan[255];
        int pos = s_scan[tid] - cnt;
        for (int j = 0; j < S; ++j)
            if (s_idx[tid * S + j] == k) s_list[pos++] = base + tid * S + j;
        __syncthreads();
        for (int j = 0; j < total; ++j) {
            const int pid = s_list[j];
            float4 v = *(const float4*)&src[(size_t)pid * DIM + tid * 4];
            acc.x += v.x; acc.y += v.y; acc.z += v.z; acc.w += v.w;
        }
        nk += total;
    }
    if (addC) {   // src was post-update residual: add back nk * C[k]
        float4 c = *(const float4*)&cb[(size_t)k * DIM + tid * 4];
        float fn = (float)nk;
        acc.x += fn * c.x; acc.y += fn * c.y; acc.z += fn * c.z; acc.w += fn * c.w;
    }
    *(float4*)&sums_out[(size_t)k * DIM + tid * 4] = acc;
    if (tid == 0) counts_out[k] = nk;
}

// ---------------- z_q_st = z_e - r2 + C2[idx2] (in-place on zq/r2 buffer) ----------------
__global__ __launch_bounds__(256) void zq_kernel(const float* __restrict__ z_e,
                                                 const float* __restrict__ cb2,
                                                 const int* __restrict__ idx2,
                                                 float* __restrict__ zq) {
    const int total = NPTS * (DIM / 4);   // float4 count = 16777216
    for (int i = blockIdx.x * 256 + threadIdx.x; i < total; i += gridDim.x * 256) {
        const size_t e = (size_t)i * 4;
        const int p = (int)(e >> 10);
        const int d = (int)(e & 1023);
        const int w = idx2[p];
        float4 z = *(const float4*)&z_e[e];
        float4 r = *(const float4*)&zq[e];
        float4 c = *(const float4*)&cb2[(size_t)w * DIM + d];
        float4 o;
        o.x = z.x - r.x + c.x; o.y = z.y - r.y + c.y;
        o.z = z.z - r.z + c.z; o.w = z.w - r.w + c.w;
        *(float4*)&zq[e] = o;
    }
}

// ---------------- n[l] = sum_k (0.99*ema_cluster + 0.01*counts) ----------------
__global__ __launch_bounds__(512) void nsum_kernel(const float* __restrict__ ec,
                                                   const int* __restrict__ counts,
                                                   float* __restrict__ n_ws) {
    __shared__ float sd[512];
    const int l = blockIdx.x, tid = threadIdx.x;
    sd[tid] = 0.99f * ec[l * NCODE + tid] + 0.01f * (float)counts[l * NCODE + tid];
    __syncthreads();
    for (int o = 256; o > 0; o >>= 1) { if (tid < o) sd[tid] += sd[tid+o]; __syncthreads(); }
    if (tid == 0) n_ws[l] = sd[0];
}

// ---------------- new_codebooks = (0.99*ema_w + 0.01*sums) / cs_norm ----------------
__global__ __launch_bounds__(256) void newcb_kernel(const float* __restrict__ ema_w,
                                                    const float* __restrict__ sums,
                                                    const float* __restrict__ ec,
                                                    const int* __restrict__ counts,
                                                    const float* __restrict__ n_ws,
                                                    float* __restrict__ out_cb) {
    const int b = blockIdx.x;          // l*512 + k
    const int tid = threadIdx.x;
    const int l = b >> 9;
    const float cs = 0.99f * ec[b] + 0.01f * (float)counts[b];
    const float n = n_ws[l];
    const float csn = (cs + 1e-5f) / (n + 512.0f * 1e-5f) * n;
    const size_t off = (size_t)b * DIM + tid * 4;
    float4 w = *(const float4*)&ema_w[off];
    float4 s4 = *(const float4*)&sums[off];
    float4 o;
    o.x = (0.99f * w.x + 0.01f * s4.x) / csn;
    o.y = (0.99f * w.y + 0.01f * s4.y) / csn;
    o.z = (0.99f * w.z + 0.01f * s4.z) / csn;
    o.w = (0.99f * w.w + 0.01f * s4.w) / csn;
    *(float4*)&out_cb[off] = o;
}

// ---------------- loss scalar ----------------
__global__ __launch_bounds__(256) void loss_kernel(const float* __restrict__ lp,
                                                   float* __restrict__ out_loss) {
    __shared__ double sd[256];
    const int tid = threadIdx.x;
    const double commit[3] = {0.25, 0.5, 1.0};
    double acc = 0.0;
    for (int l = 0; l < NLVL; ++l) {
        double s = 0.0;
        for (int j = tid; j < 512; j += 256) s += (double)lp[l * 512 + j];
        sd[tid] = s;
        __syncthreads();
        for (int o = 128; o > 0; o >>= 1) { if (tid < o) sd[tid] += sd[tid+o]; __syncthreads(); }
        if (tid == 0) acc += commit[l] * sd[0] / 67108864.0;
        __syncthreads();
    }
    if (tid == 0) *out_loss = (float)acc;
}

// ---------------- launcher ----------------
extern "C" void kernel_launch(void* const* d_in, const int* in_sizes, int n_in,
                              void* d_out, int out_size, void* d_ws, size_t ws_size,
                              hipStream_t stream) {
    const float* z_e   = (const float*)d_in[0];   // [16,4096,1024]
    const float* cbs   = (const float*)d_in[1];   // [3,512,1024]
    const float* ema_c = (const float*)d_in[2];   // [3,512]
    const float* ema_w = (const float*)d_in[3];   // [3,512,1024]
    float* out = (float*)d_out;

    char* ws = (char*)d_ws;
    int*   ws_idx = (int*)ws;                      // 3*65536 ints      (786432 B)
    float* cnorm  = (float*)(ws + 786432);         // 1536 floats
    int*   counts = (int*)(ws + 792576);           // 1536 ints
    float* lossp  = (float*)(ws + 798720);         // 3*512 floats used (3*1024 reserved)
    float* n_ws   = (float*)(ws + 811008);         // 3 floats (pad to 16)
    float* sums   = (float*)(ws + 811024);         // 3*512*1024 floats (~6 MB)
    char*  planes = (char*)(ws + 811024);          // bf16 hi/lo planes OVERLAY sums:
                                                   // plane[l] (2 MB) dead before sums[l] written

    float* zq       = out + ZQ_OFF;     // doubles as residual buffer
    float* out_loss = out + LOSS_OFF;
    float* out_idx  = out + IDX_OFF;
    float* out_cb   = out + CB_OFF;

    const float* cb0 = cbs;
    const float* cb1 = cbs + (size_t)1 * NCODE * DIM;
    const float* cb2 = cbs + (size_t)2 * NCODE * DIM;

    u16* ph0 = (u16*)(planes);                     u16* pl0 = ph0 + NCODE * DIM;
    u16* ph1 = (u16*)(planes + 2097152);           u16* pl1 = ph1 + NCODE * DIM;
    u16* ph2 = (u16*)(planes + 2 * 2097152);       u16* pl2 = ph2 + NCODE * DIM;

    cvtcb_kernel<<<NLVL * NCODE, 256, 0, stream>>>(cbs, planes);
    cnorm_kernel<<<NLVL * NCODE, 256, 0, stream>>>(cbs, cnorm);

    // level 0: r_in = z_e, r1 -> zq buffer
    level_kernel<<<NPTS / PB, NTHR2, 0, stream>>>(z_e, zq, cb0, ph0, pl0, cnorm,
                                                  out_idx, ws_idx, lossp);
    // sums_0 over pre-residual = z_e (overwrites plane 0 region — plane 0 dead)
    sums_kernel<<<NCODE, 256, 0, stream>>>(ws_idx, z_e, nullptr, 0,
                                           sums, counts);
    // level 1: in-place r1 -> r2 in zq buffer
    level_kernel<<<NPTS / PB, NTHR2, 0, stream>>>(zq, zq, cb1, ph1, pl1, cnorm + NCODE,
                                                  out_idx + NPTS, ws_idx + NPTS, lossp + 512);
    // sums_1 via post-residual trick: sum(r2 in bucket) + nk*C1[k]
    sums_kernel<<<NCODE, 256, 0, stream>>>(ws_idx + NPTS, zq, cb1, 1,
                                           sums + (size_t)NCODE * DIM, counts + NCODE);
    // level 2: r_in = r2 (kept intact), residual only in registers
    level_kernel<<<NPTS / PB, NTHR2, 0, stream>>>(zq, nullptr, cb2, ph2, pl2, cnorm + 2 * NCODE,
                                                  out_idx + 2 * NPTS, ws_idx + 2 * NPTS, lossp + 1024);
    // sums_2 over pre-residual = r2 (still intact in zq buffer)
    sums_kernel<<<NCODE, 256, 0, stream>>>(ws_idx + 2 * NPTS, zq, nullptr, 0,
                                           sums + (size_t)2 * NCODE * DIM, counts + 2 * NCODE);
    // z_q_st = z_e - r2 + C2[idx2], in-place overwrite of zq buffer
    zq_kernel<<<4096, 256, 0, stream>>>(z_e, cb2, ws_idx + 2 * NPTS, zq);

    nsum_kernel<<<NLVL, 512, 0, stream>>>(ema_c, counts, n_ws);
    newcb_kernel<<<NLVL * NCODE, 256, 0, stream>>>(ema_w, sums, ema_c, counts, n_ws, out_cb);
    loss_kernel<<<1, 256, 0, stream>>>(lossp, out_loss);
}